// Round 12
// baseline (469.141 us; speedup 1.0000x reference)
//
#include <hip/hip_runtime.h>
#include <hip/hip_bf16.h>

#define N_NODES 50000
#define N_EDGES 800000
#define NFEAT   512
#define NHID    64
#define NHEADS  8
#define NCLASS  40
#define HD      (NHEADS*NHID)   // 512
#define ALPHA   0.2f
#define EPS_F   1e-16f
#define NCHUNK  ((N_NODES + 255)/256)   // 196

typedef __attribute__((ext_vector_type(8))) short short8;
typedef __attribute__((ext_vector_type(4))) float floatx4;

__device__ __forceinline__ float bf2f(unsigned short u) {
    union { unsigned int i; float f; } v; v.i = ((unsigned int)u) << 16; return v.f;
}
__device__ __forceinline__ unsigned short f2bf(float f) {
    union { __hip_bfloat16 h; unsigned short u; } cv;
    cv.h = __float2bfloat16(f);
    return cv.u;
}

// async global->LDS, 16B per lane; LDS dest is wave-uniform base + lane*16.
__device__ __forceinline__ void gload16(const unsigned short* g, short* l) {
    __builtin_amdgcn_global_load_lds(
        (const __attribute__((address_space(1))) void*)g,
        (__attribute__((address_space(3))) void*)l,
        16, 0, 0);
}

// ---------------------------------------------------------------------------
// Merged prep: x fp32 -> xb bf16 (streaming), W_heads -> Wrb (B^T bf16),
// W_out -> Wob (padded B^T bf16), zero deg. One launch.
__global__ __launch_bounds__(256) void prep(const float* __restrict__ x,
                                            unsigned short* __restrict__ xb,
                                            const float* __restrict__ Wh,
                                            unsigned short* __restrict__ Wrb,
                                            const float* __restrict__ Wo,
                                            unsigned short* __restrict__ Wob,
                                            int* __restrict__ deg) {
    int idx = blockIdx.x*256 + threadIdx.x;
    if (idx < N_NODES*64) {                      // convx: group of 8 elems
        const float* s = x + (size_t)idx*8;
        float4 a = *(const float4*)s, b = *(const float4*)(s+4);
        short8 h;
        h[0] = (short)f2bf(a.x); h[1] = (short)f2bf(a.y);
        h[2] = (short)f2bf(a.z); h[3] = (short)f2bf(a.w);
        h[4] = (short)f2bf(b.x); h[5] = (short)f2bf(b.y);
        h[6] = (short)f2bf(b.z); h[7] = (short)f2bf(b.w);
        *(short8*)(xb + (size_t)idx*8) = h;
    }
    if (idx < N_NODES) deg[idx] = 0;
    if (idx < 512*512) {
        int n = idx >> 9, k = idx & 511;
        int hd = n >> 6, d = n & 63;
        Wrb[idx] = f2bf(Wh[(size_t)hd*NFEAT*NHID + (size_t)k*NHID + d]);
    }
    if (idx < 64*512) {
        int n = idx >> 9, k = idx & 511;
        float v = (n < NCLASS) ? Wo[(size_t)k*NCLASS + n] : 0.f;
        Wob[idx] = f2bf(v);
    }
}

// ---------------------------------------------------------------------------
// Layer-1 MFMA GEMM: 512 thr / 8 waves (2m x 4n), tile 128x256, BK=64,
// swizzled global_load_lds staging (linear LDS dest, source granule ^ row&7,
// read granule ^ lrow&7). Each wave owns 64r x 64c = one full head ->
// fused attention-dots epilogue stays wave-local.
// Natural head-major BF16 H1 (fp8 H1 failed absmax 1.66e-2 > 1.29e-2, r11).
__global__ __launch_bounds__(512) void mfma_gemm1(const unsigned short* __restrict__ Abf,
                                                  const unsigned short* __restrict__ Bbf,
                                                  const float* __restrict__ a_heads,
                                                  unsigned short* __restrict__ H1,
                                                  float* __restrict__ srcdot,
                                                  float* __restrict__ dstdot, int M) {
    int id = blockIdx.x;
    int rb = (id >> 4)*8 + (id & 7);     // row tile (XCD swizzle)
    int cb = (id >> 3) & 1;              // 2 col tiles
    int row0 = rb * 128, col0 = cb * 256;
    if (row0 >= M) return;

    __shared__ short Asl[128*64];        // 16KB
    __shared__ short Bsl[256*64];        // 32KB
    int tid  = threadIdx.x;
    int wid  = tid >> 6, lane = tid & 63;
    int lrow = lane & 15, quad = lane >> 4;
    int wm = wid >> 2, wn = wid & 3;     // 2 x 4 wave grid

    // staging: 48 chunks of 8 rows (A:0..15, B:16..47), 6 per wave.
    int lr = lane >> 3, g = lane & 7;
    int gg8 = (g ^ lr) << 3;             // k-offset in shorts
    const unsigned short* gp[6];
    short* lp[6];
#pragma unroll
    for (int i = 0; i < 6; ++i) {
        int cq = wid*6 + i;              // 0..47
        if (cq < 16) {
            int r = cq*8 + lr;
            int arow = row0 + r; arow = arow < M ? arow : M - 1;
            gp[i] = Abf + (size_t)arow*512 + gg8;
            lp[i] = &Asl[(cq*8)*64];
        } else {
            int r = (cq - 16)*8 + lr;    // 0..255
            gp[i] = Bbf + (size_t)(col0 + r)*512 + gg8;
            lp[i] = &Bsl[((cq - 16)*8)*64];
        }
    }

    floatx4 acc[4][4];
#pragma unroll
    for (int mm = 0; mm < 4; mm++)
#pragma unroll
        for (int nn = 0; nn < 4; nn++) acc[mm][nn] = (floatx4){0.f,0.f,0.f,0.f};

    for (int k0 = 0; k0 < 512; k0 += 64) {
#pragma unroll
        for (int i = 0; i < 6; ++i)
            gload16(gp[i] + k0, lp[i]);
        __syncthreads();                 // vmcnt(0) drain lands here
#pragma unroll
        for (int ks = 0; ks < 2; ++ks) {
            int gsw = ((ks*4 + quad) ^ (lrow & 7)) * 8;
            short8 af[4], bfr[4];
#pragma unroll
            for (int mm = 0; mm < 4; ++mm)
                af[mm] = *(const short8*)(&Asl[(wm*64 + mm*16 + lrow)*64 + gsw]);
#pragma unroll
            for (int nn = 0; nn < 4; ++nn)
                bfr[nn] = *(const short8*)(&Bsl[(wn*64 + nn*16 + lrow)*64 + gsw]);
#pragma unroll
            for (int mm = 0; mm < 4; ++mm)
#pragma unroll
                for (int nn = 0; nn < 4; ++nn)
                    acc[mm][nn] = __builtin_amdgcn_mfma_f32_16x16x32_bf16(
                        af[mm], bfr[nn], acc[mm][nn], 0, 0, 0);
        }
        __syncthreads();
    }

    // ---- fused attention dots for this wave's head = cb*4 + wn ----
    {
        int head = (col0 >> 6) + wn;
        float a0v[4], a1v[4];
#pragma unroll
        for (int nn = 0; nn < 4; ++nn) {
            a0v[nn] = a_heads[head*128 + nn*16 + lrow];
            a1v[nn] = a_heads[head*128 + 64 + nn*16 + lrow];
        }
#pragma unroll
        for (int mm = 0; mm < 4; ++mm) {
#pragma unroll
            for (int r = 0; r < 4; ++r) {
                float s0 = 0.f, s1 = 0.f;
#pragma unroll
                for (int nn = 0; nn < 4; ++nn) {
                    float v = acc[mm][nn][r];
                    s0 = fmaf(v, a0v[nn], s0);
                    s1 = fmaf(v, a1v[nn], s1);
                }
#pragma unroll
                for (int off = 1; off < 16; off <<= 1) {
                    s0 += __shfl_xor(s0, off, 64);
                    s1 += __shfl_xor(s1, off, 64);
                }
                int grow = row0 + wm*64 + mm*16 + quad*4 + r;
                if (lrow == 0 && grow < M) {
                    srcdot[(size_t)grow*8 + head] = s0;
                    dstdot[(size_t)grow*8 + head] = s1;
                }
            }
        }
    }

    // ---- natural-layout C write: 16 consecutive ushorts per (mm,nn,r) ----
#pragma unroll
    for (int mm = 0; mm < 4; ++mm) {
        int rbase = row0 + wm*64 + mm*16 + quad*4;
#pragma unroll
        for (int r = 0; r < 4; ++r) {
            int grow = rbase + r;
            if (grow < M) {
#pragma unroll
                for (int nn = 0; nn < 4; ++nn) {
                    int c = col0 + wn*64 + nn*16 + lrow;
                    H1[(size_t)grow*512 + c] = f2bf(acc[mm][nn][r]);
                }
            }
        }
    }
}

// ---------------------------------------------------------------------------
// Layer-2 MFMA GEMM, BK=64 + swizzled staging. 512 thr / 8 waves, 128x64
// tile; each wave owns 16 rows x all 64 cols (acc[4]). Output H2 in BF16;
// fused final-dots epilogue from f32 acc.
__global__ __launch_bounds__(512) void mfma_gemm2(const unsigned short* __restrict__ Abf,
                                                  const unsigned short* __restrict__ Bbf,
                                                  const float* __restrict__ a_out,
                                                  unsigned short* __restrict__ H2b,
                                                  float* __restrict__ src2,
                                                  float* __restrict__ dst2, int M) {
    __shared__ short Asl[128*64];   // 16KB
    __shared__ short Bsl[64*64];    //  8KB
    int tid  = threadIdx.x;
    int wid  = tid >> 6, lane = tid & 63;
    int lrow = lane & 15, quad = lane >> 4;
    int row0 = blockIdx.x * 128;
    if (row0 >= M) return;

    int lr = lane >> 3, g = lane & 7;
    int gg8 = (g ^ lr) << 3;
    int ar0 = row0 + wid*16 + lr;     ar0 = ar0 < M ? ar0 : M - 1;
    int ar1 = row0 + wid*16 + 8 + lr; ar1 = ar1 < M ? ar1 : M - 1;
    const unsigned short* agp0 = Abf + (size_t)ar0*512 + gg8;
    const unsigned short* agp1 = Abf + (size_t)ar1*512 + gg8;
    const unsigned short* bgp  = Bbf + (size_t)(wid*8 + lr)*512 + gg8;
    short* al0 = &Asl[(wid*16)*64];
    short* al1 = &Asl[(wid*16 + 8)*64];
    short* bl  = &Bsl[(wid*8)*64];

    floatx4 acc[4];
#pragma unroll
    for (int nn = 0; nn < 4; nn++) acc[nn] = (floatx4){0.f,0.f,0.f,0.f};

    for (int k0 = 0; k0 < 512; k0 += 64) {
        gload16(agp0 + k0, al0);
        gload16(agp1 + k0, al1);
        gload16(bgp + k0, bl);
        __syncthreads();
#pragma unroll
        for (int ks = 0; ks < 2; ++ks) {
            int gsw = ((ks*4 + quad) ^ (lrow & 7)) * 8;
            short8 af, bfr[4];
            af = *(const short8*)(&Asl[(wid*16 + lrow)*64 + gsw]);
#pragma unroll
            for (int nn = 0; nn < 4; ++nn)
                bfr[nn] = *(const short8*)(&Bsl[(nn*16 + lrow)*64 + gsw]);
#pragma unroll
            for (int nn = 0; nn < 4; ++nn)
                acc[nn] = __builtin_amdgcn_mfma_f32_16x16x32_bf16(
                    af, bfr[nn], acc[nn], 0, 0, 0);
        }
        __syncthreads();
    }

    // ---- fused final attention dots (f32 acc; cols 40..63 are exactly 0) ----
    {
        float a0v[4], a1v[4];
#pragma unroll
        for (int nn = 0; nn < 4; ++nn) {
            int c = nn*16 + lrow;
            a0v[nn] = c < NCLASS ? a_out[c] : 0.f;
            a1v[nn] = c < NCLASS ? a_out[NCLASS + c] : 0.f;
        }
#pragma unroll
        for (int r = 0; r < 4; ++r) {
            float s0 = 0.f, s1 = 0.f;
#pragma unroll
            for (int nn = 0; nn < 4; ++nn) {
                float v = acc[nn][r];
                s0 = fmaf(v, a0v[nn], s0);
                s1 = fmaf(v, a1v[nn], s1);
            }
#pragma unroll
            for (int off = 1; off < 16; off <<= 1) {
                s0 += __shfl_xor(s0, off, 64);
                s1 += __shfl_xor(s1, off, 64);
            }
            int grow = row0 + wid*16 + quad*4 + r;
            if (lrow == 0 && grow < M) {
                src2[grow] = s0;
                dst2[grow] = s1;
            }
        }
    }

#pragma unroll
    for (int nn = 0; nn < 4; ++nn) {
        int c = nn*16 + lrow;
#pragma unroll
        for (int r = 0; r < 4; ++r) {
            int grow = row0 + wid*16 + quad*4 + r;
            if (grow < M)
                H2b[(size_t)grow*64 + c] = f2bf(acc[nn][r]);
        }
    }
}

// ---------------------------------------------------------------------------
// CSR build
__global__ void histk(const int* __restrict__ row, int* __restrict__ deg) {
    int e = blockIdx.x*256 + threadIdx.x;
    if (e < N_EDGES) atomicAdd(&deg[row[e]], 1);
}
__global__ void scanA(const int* __restrict__ deg, int* __restrict__ row_ptr,
                      int* __restrict__ chunk_tot) {
    __shared__ int s[256];
    int t = threadIdx.x;
    int idx = blockIdx.x*256 + t;
    int v = (idx < N_NODES) ? deg[idx] : 0;
    s[t] = v;
    __syncthreads();
#pragma unroll
    for (int off = 1; off < 256; off <<= 1) {
        int x = (t >= off) ? s[t-off] : 0;
        __syncthreads();
        s[t] += x;
        __syncthreads();
    }
    if (idx < N_NODES) row_ptr[idx] = s[t] - v;
    if (t == 255) chunk_tot[blockIdx.x] = s[t];
}
__global__ void scanB(const int* __restrict__ chunk_tot, int* __restrict__ chunk_off,
                      int* __restrict__ row_ptr) {
    __shared__ int s[256];
    int t = threadIdx.x;
    int v = (t < NCHUNK) ? chunk_tot[t] : 0;
    s[t] = v;
    __syncthreads();
#pragma unroll
    for (int off = 1; off < 256; off <<= 1) {
        int x = (t >= off) ? s[t-off] : 0;
        __syncthreads();
        s[t] += x;
        __syncthreads();
    }
    if (t < NCHUNK) chunk_off[t] = s[t] - v;
    if (t == 255) row_ptr[N_NODES] = s[t];
}
__global__ void scanC(const int* __restrict__ chunk_off, int* __restrict__ row_ptr,
                      int* __restrict__ cursor) {
    int idx = blockIdx.x*256 + threadIdx.x;
    if (idx < N_NODES) {
        int rp = row_ptr[idx] + chunk_off[idx >> 8];
        row_ptr[idx] = rp;
        cursor[idx] = rp;
    }
}

// Pure CSR fill (edge weights recomputed per-lane in agg1: head-major layout
// means 1 expf/lane/edge, unlike round-1's 8 — Wcsr eliminated entirely).
__global__ void fillk(const int* __restrict__ row, const int* __restrict__ col,
                      int* __restrict__ cursor, int* __restrict__ csr_col) {
    int e = blockIdx.x*256 + threadIdx.x;
    if (e >= N_EDGES) return;
    int r = row[e], c = col[e];
    int pos = atomicAdd(&cursor[r], 1);
    csr_col[pos] = c;
}

// ---------------------------------------------------------------------------
// Layer-1 aggregation + ELU, NATURAL head-major BF16 H1.
// Byte-bound at ~3.7 TB/s (invariant across VALU 27-40%, occ 45-68%);
// dropping the 25.6MB Wcsr stream is the remaining byte lever.
// Lane l owns head hd=l>>3: weight = exp(-lrelu(srcdot[i,hd]+dstdot[c,hd]))
// recomputed in-lane (1 expf/edge/lane; dstdot is 1.6MB L2-resident,
// 64 lanes touch one 32B line per edge). Bit-identical to old fillk_w1 math.
__global__ __launch_bounds__(256) void agg1(const unsigned short* __restrict__ H1,
                                            const float* __restrict__ srcdot,
                                            const float* __restrict__ dstdot,
                                            const int* __restrict__ row_ptr,
                                            const int* __restrict__ csr_col,
                                            unsigned short* __restrict__ hcatb) {
    int wave = (blockIdx.x*256 + threadIdx.x) >> 6;
    int lane = threadIdx.x & 63;
    if (wave >= N_NODES) return;
    int start = row_ptr[wave], end = row_ptr[wave+1];
    int hd = lane >> 3;              // head owned by this lane
    float sd = srcdot[(size_t)wave*8 + hd];
    float acc[8];
    float den = 0.f;
#pragma unroll
    for (int j = 0; j < 8; j++) acc[j] = 0.f;

#define W_OF(DD) ({ float t_ = sd + (DD); t_ = t_ > 0.f ? t_ : ALPHA*t_; __expf(-t_); })

    int k = start;
    for (; k + 4 <= end; k += 4) {
        int c0 = csr_col[k],   c1 = csr_col[k+1];
        int c2 = csr_col[k+2], c3 = csr_col[k+3];
        short8 hv0 = *(const short8*)(H1 + (size_t)c0*512 + lane*8);
        short8 hv1 = *(const short8*)(H1 + (size_t)c1*512 + lane*8);
        short8 hv2 = *(const short8*)(H1 + (size_t)c2*512 + lane*8);
        short8 hv3 = *(const short8*)(H1 + (size_t)c3*512 + lane*8);
        float d0 = dstdot[(size_t)c0*8 + hd];
        float d1 = dstdot[(size_t)c1*8 + hd];
        float d2 = dstdot[(size_t)c2*8 + hd];
        float d3 = dstdot[(size_t)c3*8 + hd];
        float w0 = W_OF(d0), w1 = W_OF(d1), w2 = W_OF(d2), w3 = W_OF(d3);
        den += (w0 + w1) + (w2 + w3);
#pragma unroll
        for (int j = 0; j < 8; j++) {
            acc[j] = fmaf(w0, bf2f((unsigned short)hv0[j]), acc[j]);
            acc[j] = fmaf(w1, bf2f((unsigned short)hv1[j]), acc[j]);
            acc[j] = fmaf(w2, bf2f((unsigned short)hv2[j]), acc[j]);
            acc[j] = fmaf(w3, bf2f((unsigned short)hv3[j]), acc[j]);
        }
    }
    for (; k < end; ++k) {
        int c = csr_col[k];
        short8 hv = *(const short8*)(H1 + (size_t)c*512 + lane*8);
        float w = W_OF(dstdot[(size_t)c*8 + hd]);
        den += w;
#pragma unroll
        for (int j = 0; j < 8; j++)
            acc[j] = fmaf(w, bf2f((unsigned short)hv[j]), acc[j]);
    }
#undef W_OF
    float rden = 1.f / (den + EPS_F);
    short8 o8;
#pragma unroll
    for (int j = 0; j < 8; j++) {
        float o = acc[j] * rden;
        o = o > 0.f ? o : (__expf(o) - 1.f);   // ELU
        o8[j] = (short)f2bf(o);
    }
    *(short8*)(hcatb + (size_t)wave*HD + lane*8) = o8;
}

// ---------------------------------------------------------------------------
// Final aggregation, software-pipelined (8-edge x 2-color batches).
// H2 is bf16: one 128B line per edge-gather.
__global__ __launch_bounds__(256) void agg2(const unsigned short* __restrict__ H2b,
                                            const float* __restrict__ src2,
                                            const float* __restrict__ dst2,
                                            const int* __restrict__ row_ptr,
                                            const int* __restrict__ csr_col,
                                            float* __restrict__ out) {
    int wave = (blockIdx.x*256 + threadIdx.x) >> 6;
    int lane = threadIdx.x & 63;
    if (wave >= N_NODES) return;
    int start = row_ptr[wave], end = row_ptr[wave+1];
    int deg = end - start;
    float s2i = src2[wave];
    int l = lane < NCLASS ? lane : 0;
    float acc = 0.f, den = 0.f;

    int colreg = 0;
    if (deg > 0) colreg = csr_col[start + (lane < deg ? lane : deg - 1)];

#define AG2_G1(T, H, IDX) do { \
    int cg_ = __builtin_amdgcn_readlane(colreg, (IDX)); \
    T = dst2[cg_]; \
    H = bf2f(H2b[(size_t)cg_*64 + l]); \
} while(0)
#define AG2_C1(T, H) do { \
    float t_ = s2i + (T); \
    t_ = t_ > 0.f ? t_ : ALPHA*t_; \
    float w_ = __expf(-t_); \
    den += w_; acc = fmaf(w_, (H), acc); \
} while(0)
#define AG2_G8(T0,T1,T2,T3,T4,T5,T6,T7,H0,H1,H2,H3,H4,H5,H6,H7,BASE) do { \
    AG2_G1(T0,H0,(BASE));   AG2_G1(T1,H1,(BASE)+1); \
    AG2_G1(T2,H2,(BASE)+2); AG2_G1(T3,H3,(BASE)+3); \
    AG2_G1(T4,H4,(BASE)+4); AG2_G1(T5,H5,(BASE)+5); \
    AG2_G1(T6,H6,(BASE)+6); AG2_G1(T7,H7,(BASE)+7); \
} while(0)
#define AG2_C8(T0,T1,T2,T3,T4,T5,T6,T7,H0,H1,H2,H3,H4,H5,H6,H7) do { \
    AG2_C1(T0,H0); AG2_C1(T1,H1); AG2_C1(T2,H2); AG2_C1(T3,H3); \
    AG2_C1(T4,H4); AG2_C1(T5,H5); AG2_C1(T6,H6); AG2_C1(T7,H7); \
} while(0)

    int lim = deg < 64 ? deg : 64;
    int nb = lim >> 3;
    int k = start;
    float ta0,ta1,ta2,ta3,ta4,ta5,ta6,ta7, ga0,ga1,ga2,ga3,ga4,ga5,ga6,ga7;
    float tb0,tb1,tb2,tb3,tb4,tb5,tb6,tb7, gb0,gb1,gb2,gb3,gb4,gb5,gb6,gb7;
    if (nb > 0) {
        AG2_G8(ta0,ta1,ta2,ta3,ta4,ta5,ta6,ta7, ga0,ga1,ga2,ga3,ga4,ga5,ga6,ga7, 0);
        int b = 1;
        for (; b + 1 < nb; b += 2) {
            AG2_G8(tb0,tb1,tb2,tb3,tb4,tb5,tb6,tb7, gb0,gb1,gb2,gb3,gb4,gb5,gb6,gb7, b*8);
            AG2_C8(ta0,ta1,ta2,ta3,ta4,ta5,ta6,ta7, ga0,ga1,ga2,ga3,ga4,ga5,ga6,ga7);
            AG2_G8(ta0,ta1,ta2,ta3,ta4,ta5,ta6,ta7, ga0,ga1,ga2,ga3,ga4,ga5,ga6,ga7, (b+1)*8);
            AG2_C8(tb0,tb1,tb2,tb3,tb4,tb5,tb6,tb7, gb0,gb1,gb2,gb3,gb4,gb5,gb6,gb7);
        }
        if (b < nb) {
            AG2_G8(tb0,tb1,tb2,tb3,tb4,tb5,tb6,tb7, gb0,gb1,gb2,gb3,gb4,gb5,gb6,gb7, b*8);
            AG2_C8(ta0,ta1,ta2,ta3,ta4,ta5,ta6,ta7, ga0,ga1,ga2,ga3,ga4,ga5,ga6,ga7);
            AG2_C8(tb0,tb1,tb2,tb3,tb4,tb5,tb6,tb7, gb0,gb1,gb2,gb3,gb4,gb5,gb6,gb7);
        } else {
            AG2_C8(ta0,ta1,ta2,ta3,ta4,ta5,ta6,ta7, ga0,ga1,ga2,ga3,ga4,ga5,ga6,ga7);
        }
        k = start + nb*8;
    }
    for (; k < end; ++k) {
        int c_ = (k - start < 64) ? __builtin_amdgcn_readlane(colreg, k - start)
                                  : csr_col[k];
        float t = dst2[c_];
        float h = bf2f(H2b[(size_t)c_*64 + l]);
        AG2_C1(t, h);
    }
#undef AG2_G1
#undef AG2_C1
#undef AG2_G8
#undef AG2_C8

    if (lane < NCLASS)
        out[(size_t)wave*NCLASS + lane] = acc / (den + EPS_F);
}

// ---------------------------------------------------------------------------
extern "C" void kernel_launch(void* const* d_in, const int* in_sizes, int n_in,
                              void* d_out, int out_size, void* d_ws, size_t ws_size,
                              hipStream_t stream) {
    const float* x       = (const float*)d_in[0];
    const float* W_heads = (const float*)d_in[1];
    const float* a_heads = (const float*)d_in[2];
    const float* W_out   = (const float*)d_in[3];
    const float* a_out   = (const float*)d_in[4];
    const int*   ei      = (const int*)d_in[5];
    const int*   row     = ei;
    const int*   col     = ei + N_EDGES;
    float* out = (float*)d_out;

    char* ws = (char*)d_ws;
    size_t off = 0;
    auto alloc = [&](size_t bytes) {
        char* p = ws + off;
        off = (off + bytes + 255) & ~(size_t)255;
        return p;
    };
    unsigned short* Wrb   = (unsigned short*)alloc((size_t)512*512*2);
    unsigned short* Wob   = (unsigned short*)alloc((size_t)64*512*2);
    unsigned short* H1    = (unsigned short*)alloc((size_t)N_NODES*HD*2);
    unsigned short* xb    = (unsigned short*)alloc((size_t)N_NODES*NFEAT*2);
    unsigned short* hcatb = xb;   // alias: xb dead after gemm1, hcatb born at agg1
    float* srcdot  = (float*)alloc((size_t)N_NODES*NHEADS*4);
    float* dstdot  = (float*)alloc((size_t)N_NODES*NHEADS*4);
    int*   deg     = (int*)alloc((size_t)N_NODES*4);
    int*   row_ptr = (int*)alloc((size_t)(N_NODES+1)*4);
    int*   cursor  = (int*)alloc((size_t)N_NODES*4);
    int*   ctot    = (int*)alloc(256*4);
    int*   coff    = (int*)alloc(256*4);
    int*   csr_col = (int*)alloc((size_t)N_EDGES*4);
    unsigned short* H2b = (unsigned short*)alloc((size_t)N_NODES*64*2);
    float* src2    = (float*)alloc((size_t)N_NODES*4);
    float* dst2    = (float*)alloc((size_t)N_NODES*4);
    (void)ws_size;

    const int EB = (N_EDGES + 255)/256;
    const int WB = (N_NODES*64 + 255)/256;   // wave-per-node grids

    // Layer 1 (gemm1 also produces srcdot/dstdot)
    prep<<<(N_NODES*64 + 255)/256, 256, 0, stream>>>(x, xb, W_heads, Wrb,
                                                     W_out, Wob, deg);
    {
        int rtiles = (N_NODES + 127)/128;            // 391
        int nblk = ((rtiles + 7)/8) * 16;            // 784 (2 col tiles)
        mfma_gemm1<<<nblk, 512, 0, stream>>>(xb, Wrb, a_heads, H1,
                                             srcdot, dstdot, N_NODES);
    }

    // CSR build (weights recomputed in agg1)
    histk<<<EB, 256, 0, stream>>>(row, deg);
    scanA<<<NCHUNK, 256, 0, stream>>>(deg, row_ptr, ctot);
    scanB<<<1, 256, 0, stream>>>(ctot, coff, row_ptr);
    scanC<<<NCHUNK, 256, 0, stream>>>(coff, row_ptr, cursor);
    fillk<<<EB, 256, 0, stream>>>(row, col, cursor, csr_col);

    agg1<<<WB, 256, 0, stream>>>(H1, srcdot, dstdot, row_ptr, csr_col, hcatb);

    // Layer 2 (gemm2 also produces src2/dst2)
    mfma_gemm2<<<(N_NODES + 127)/128, 512, 0, stream>>>(hcatb, Wob, a_out,
                                                        H2b, src2, dst2, N_NODES);
    agg2<<<WB, 256, 0, stream>>>(H2b, src2, dst2, row_ptr, csr_col, out);
}

// Round 13
// 465.344 us; speedup vs baseline: 1.0082x; 1.0082x over previous
//
#include <hip/hip_runtime.h>
#include <hip/hip_bf16.h>

#define N_NODES 50000
#define N_EDGES 800000
#define NFEAT   512
#define NHID    64
#define NHEADS  8
#define NCLASS  40
#define HD      (NHEADS*NHID)   // 512
#define ALPHA   0.2f
#define EPS_F   1e-16f
#define NCHUNK  ((N_NODES + 255)/256)   // 196

typedef __attribute__((ext_vector_type(8))) short short8;
typedef __attribute__((ext_vector_type(4))) float floatx4;

__device__ __forceinline__ float bf2f(unsigned short u) {
    union { unsigned int i; float f; } v; v.i = ((unsigned int)u) << 16; return v.f;
}
__device__ __forceinline__ unsigned short f2bf(float f) {
    union { __hip_bfloat16 h; unsigned short u; } cv;
    cv.h = __float2bfloat16(f);
    return cv.u;
}

// async global->LDS, 16B per lane; LDS dest is wave-uniform base + lane*16.
__device__ __forceinline__ void gload16(const unsigned short* g, short* l) {
    __builtin_amdgcn_global_load_lds(
        (const __attribute__((address_space(1))) void*)g,
        (__attribute__((address_space(3))) void*)l,
        16, 0, 0);
}

// ---------------------------------------------------------------------------
// Merged prep: x fp32 -> xb bf16 (streaming), W_heads -> Wrb (B^T bf16),
// W_out -> Wob (padded B^T bf16), zero deg. One launch.
__global__ __launch_bounds__(256) void prep(const float* __restrict__ x,
                                            unsigned short* __restrict__ xb,
                                            const float* __restrict__ Wh,
                                            unsigned short* __restrict__ Wrb,
                                            const float* __restrict__ Wo,
                                            unsigned short* __restrict__ Wob,
                                            int* __restrict__ deg) {
    int idx = blockIdx.x*256 + threadIdx.x;
    if (idx < N_NODES*64) {                      // convx: group of 8 elems
        const float* s = x + (size_t)idx*8;
        float4 a = *(const float4*)s, b = *(const float4*)(s+4);
        short8 h;
        h[0] = (short)f2bf(a.x); h[1] = (short)f2bf(a.y);
        h[2] = (short)f2bf(a.z); h[3] = (short)f2bf(a.w);
        h[4] = (short)f2bf(b.x); h[5] = (short)f2bf(b.y);
        h[6] = (short)f2bf(b.z); h[7] = (short)f2bf(b.w);
        *(short8*)(xb + (size_t)idx*8) = h;
    }
    if (idx < N_NODES) deg[idx] = 0;
    if (idx < 512*512) {
        int n = idx >> 9, k = idx & 511;
        int hd = n >> 6, d = n & 63;
        Wrb[idx] = f2bf(Wh[(size_t)hd*NFEAT*NHID + (size_t)k*NHID + d]);
    }
    if (idx < 64*512) {
        int n = idx >> 9, k = idx & 511;
        float v = (n < NCLASS) ? Wo[(size_t)k*NCLASS + n] : 0.f;
        Wob[idx] = f2bf(v);
    }
}

// ---------------------------------------------------------------------------
// Layer-1 MFMA GEMM: 512 thr / 8 waves (2m x 4n), tile 128x256 (col-tile 256
// -> A is re-read 2x instead of 4x), BK=64, swizzled global_load_lds staging
// (linear LDS dest, source granule ^ row&7, read granule ^ lrow&7 -> 8
// lanes/bank-slot). Each wave owns 64 rows x 64 cols = one full head ->
// fused attention-dots epilogue stays wave-local.
// Natural head-major BF16 H1 (fp8 H1 failed absmax 1.66e-2 > 1.29e-2, r11).
__global__ __launch_bounds__(512) void mfma_gemm1(const unsigned short* __restrict__ Abf,
                                                  const unsigned short* __restrict__ Bbf,
                                                  const float* __restrict__ a_heads,
                                                  unsigned short* __restrict__ H1,
                                                  float* __restrict__ srcdot,
                                                  float* __restrict__ dstdot, int M) {
    int id = blockIdx.x;
    int rb = (id >> 4)*8 + (id & 7);     // row tile (XCD swizzle)
    int cb = (id >> 3) & 1;              // 2 col tiles
    int row0 = rb * 128, col0 = cb * 256;
    if (row0 >= M) return;

    __shared__ short Asl[128*64];        // 16KB
    __shared__ short Bsl[256*64];        // 32KB
    int tid  = threadIdx.x;
    int wid  = tid >> 6, lane = tid & 63;
    int lrow = lane & 15, quad = lane >> 4;
    int wm = wid >> 2, wn = wid & 3;     // 2 x 4 wave grid

    // staging: 48 chunks of 8 rows (A:0..15, B:16..47), 6 per wave.
    int lr = lane >> 3, g = lane & 7;
    int gg8 = (g ^ lr) << 3;             // k-offset in shorts
    const unsigned short* gp[6];
    short* lp[6];
#pragma unroll
    for (int i = 0; i < 6; ++i) {
        int cq = wid*6 + i;              // 0..47
        if (cq < 16) {
            int r = cq*8 + lr;
            int arow = row0 + r; arow = arow < M ? arow : M - 1;
            gp[i] = Abf + (size_t)arow*512 + gg8;
            lp[i] = &Asl[(cq*8)*64];
        } else {
            int r = (cq - 16)*8 + lr;    // 0..255
            gp[i] = Bbf + (size_t)(col0 + r)*512 + gg8;
            lp[i] = &Bsl[((cq - 16)*8)*64];
        }
    }

    floatx4 acc[4][4];
#pragma unroll
    for (int mm = 0; mm < 4; mm++)
#pragma unroll
        for (int nn = 0; nn < 4; nn++) acc[mm][nn] = (floatx4){0.f,0.f,0.f,0.f};

    for (int k0 = 0; k0 < 512; k0 += 64) {
#pragma unroll
        for (int i = 0; i < 6; ++i)
            gload16(gp[i] + k0, lp[i]);
        __syncthreads();                 // vmcnt(0) drain lands here
#pragma unroll
        for (int ks = 0; ks < 2; ++ks) {
            int gsw = ((ks*4 + quad) ^ (lrow & 7)) * 8;
            short8 af[4], bfr[4];
#pragma unroll
            for (int mm = 0; mm < 4; ++mm)
                af[mm] = *(const short8*)(&Asl[(wm*64 + mm*16 + lrow)*64 + gsw]);
#pragma unroll
            for (int nn = 0; nn < 4; ++nn)
                bfr[nn] = *(const short8*)(&Bsl[(wn*64 + nn*16 + lrow)*64 + gsw]);
#pragma unroll
            for (int mm = 0; mm < 4; ++mm)
#pragma unroll
                for (int nn = 0; nn < 4; ++nn)
                    acc[mm][nn] = __builtin_amdgcn_mfma_f32_16x16x32_bf16(
                        af[mm], bfr[nn], acc[mm][nn], 0, 0, 0);
        }
        __syncthreads();
    }

    // ---- fused attention dots for this wave's head = cb*4 + wn ----
    {
        int head = (col0 >> 6) + wn;
        float a0v[4], a1v[4];
#pragma unroll
        for (int nn = 0; nn < 4; ++nn) {
            a0v[nn] = a_heads[head*128 + nn*16 + lrow];
            a1v[nn] = a_heads[head*128 + 64 + nn*16 + lrow];
        }
#pragma unroll
        for (int mm = 0; mm < 4; ++mm) {
#pragma unroll
            for (int r = 0; r < 4; ++r) {
                float s0 = 0.f, s1 = 0.f;
#pragma unroll
                for (int nn = 0; nn < 4; ++nn) {
                    float v = acc[mm][nn][r];
                    s0 = fmaf(v, a0v[nn], s0);
                    s1 = fmaf(v, a1v[nn], s1);
                }
#pragma unroll
                for (int off = 1; off < 16; off <<= 1) {
                    s0 += __shfl_xor(s0, off, 64);
                    s1 += __shfl_xor(s1, off, 64);
                }
                int grow = row0 + wm*64 + mm*16 + quad*4 + r;
                if (lrow == 0 && grow < M) {
                    srcdot[(size_t)grow*8 + head] = s0;
                    dstdot[(size_t)grow*8 + head] = s1;
                }
            }
        }
    }

    // ---- natural-layout C write: 16 consecutive ushorts per (mm,nn,r) ----
#pragma unroll
    for (int mm = 0; mm < 4; ++mm) {
        int rbase = row0 + wm*64 + mm*16 + quad*4;
#pragma unroll
        for (int r = 0; r < 4; ++r) {
            int grow = rbase + r;
            if (grow < M) {
#pragma unroll
                for (int nn = 0; nn < 4; ++nn) {
                    int c = col0 + wn*64 + nn*16 + lrow;
                    H1[(size_t)grow*512 + c] = f2bf(acc[mm][nn][r]);
                }
            }
        }
    }
}

// ---------------------------------------------------------------------------
// Layer-2 MFMA GEMM, BK=64 + swizzled staging. 512 thr / 8 waves, 128x64
// tile; each wave owns 16 rows x all 64 cols (acc[4]). Output H2 in BF16
// (one 128B line per agg2 gather); fused final-dots epilogue from f32 acc.
__global__ __launch_bounds__(512) void mfma_gemm2(const unsigned short* __restrict__ Abf,
                                                  const unsigned short* __restrict__ Bbf,
                                                  const float* __restrict__ a_out,
                                                  unsigned short* __restrict__ H2b,
                                                  float* __restrict__ src2,
                                                  float* __restrict__ dst2, int M) {
    __shared__ short Asl[128*64];   // 16KB
    __shared__ short Bsl[64*64];    //  8KB
    int tid  = threadIdx.x;
    int wid  = tid >> 6, lane = tid & 63;
    int lrow = lane & 15, quad = lane >> 4;
    int row0 = blockIdx.x * 128;
    if (row0 >= M) return;

    // staging: wave wid covers A chunks {2wid, 2wid+1} and B chunk wid.
    int lr = lane >> 3, g = lane & 7;
    int gg8 = (g ^ lr) << 3;
    int ar0 = row0 + wid*16 + lr;     ar0 = ar0 < M ? ar0 : M - 1;
    int ar1 = row0 + wid*16 + 8 + lr; ar1 = ar1 < M ? ar1 : M - 1;
    const unsigned short* agp0 = Abf + (size_t)ar0*512 + gg8;
    const unsigned short* agp1 = Abf + (size_t)ar1*512 + gg8;
    const unsigned short* bgp  = Bbf + (size_t)(wid*8 + lr)*512 + gg8;
    short* al0 = &Asl[(wid*16)*64];
    short* al1 = &Asl[(wid*16 + 8)*64];
    short* bl  = &Bsl[(wid*8)*64];

    floatx4 acc[4];
#pragma unroll
    for (int nn = 0; nn < 4; nn++) acc[nn] = (floatx4){0.f,0.f,0.f,0.f};

    for (int k0 = 0; k0 < 512; k0 += 64) {
        gload16(agp0 + k0, al0);
        gload16(agp1 + k0, al1);
        gload16(bgp + k0, bl);
        __syncthreads();
#pragma unroll
        for (int ks = 0; ks < 2; ++ks) {
            int gsw = ((ks*4 + quad) ^ (lrow & 7)) * 8;
            short8 af, bfr[4];
            af = *(const short8*)(&Asl[(wid*16 + lrow)*64 + gsw]);
#pragma unroll
            for (int nn = 0; nn < 4; ++nn)
                bfr[nn] = *(const short8*)(&Bsl[(nn*16 + lrow)*64 + gsw]);
#pragma unroll
            for (int nn = 0; nn < 4; ++nn)
                acc[nn] = __builtin_amdgcn_mfma_f32_16x16x32_bf16(
                    af, bfr[nn], acc[nn], 0, 0, 0);
        }
        __syncthreads();
    }

    // ---- fused final attention dots (f32 acc; cols 40..63 are exactly 0) ----
    {
        float a0v[4], a1v[4];
#pragma unroll
        for (int nn = 0; nn < 4; ++nn) {
            int c = nn*16 + lrow;
            a0v[nn] = c < NCLASS ? a_out[c] : 0.f;
            a1v[nn] = c < NCLASS ? a_out[NCLASS + c] : 0.f;
        }
#pragma unroll
        for (int r = 0; r < 4; ++r) {
            float s0 = 0.f, s1 = 0.f;
#pragma unroll
            for (int nn = 0; nn < 4; ++nn) {
                float v = acc[nn][r];
                s0 = fmaf(v, a0v[nn], s0);
                s1 = fmaf(v, a1v[nn], s1);
            }
#pragma unroll
            for (int off = 1; off < 16; off <<= 1) {
                s0 += __shfl_xor(s0, off, 64);
                s1 += __shfl_xor(s1, off, 64);
            }
            int grow = row0 + wid*16 + quad*4 + r;
            if (lrow == 0 && grow < M) {
                src2[grow] = s0;
                dst2[grow] = s1;
            }
        }
    }

#pragma unroll
    for (int nn = 0; nn < 4; ++nn) {
        int c = nn*16 + lrow;
#pragma unroll
        for (int r = 0; r < 4; ++r) {
            int grow = row0 + wid*16 + quad*4 + r;
            if (grow < M)
                H2b[(size_t)grow*64 + c] = f2bf(acc[nn][r]);
        }
    }
}

// ---------------------------------------------------------------------------
// CSR build
__global__ void histk(const int* __restrict__ row, int* __restrict__ deg) {
    int e = blockIdx.x*256 + threadIdx.x;
    if (e < N_EDGES) atomicAdd(&deg[row[e]], 1);
}
__global__ void scanA(const int* __restrict__ deg, int* __restrict__ row_ptr,
                      int* __restrict__ chunk_tot) {
    __shared__ int s[256];
    int t = threadIdx.x;
    int idx = blockIdx.x*256 + t;
    int v = (idx < N_NODES) ? deg[idx] : 0;
    s[t] = v;
    __syncthreads();
#pragma unroll
    for (int off = 1; off < 256; off <<= 1) {
        int x = (t >= off) ? s[t-off] : 0;
        __syncthreads();
        s[t] += x;
        __syncthreads();
    }
    if (idx < N_NODES) row_ptr[idx] = s[t] - v;
    if (t == 255) chunk_tot[blockIdx.x] = s[t];
}
__global__ void scanB(const int* __restrict__ chunk_tot, int* __restrict__ chunk_off,
                      int* __restrict__ row_ptr) {
    __shared__ int s[256];
    int t = threadIdx.x;
    int v = (t < NCHUNK) ? chunk_tot[t] : 0;
    s[t] = v;
    __syncthreads();
#pragma unroll
    for (int off = 1; off < 256; off <<= 1) {
        int x = (t >= off) ? s[t-off] : 0;
        __syncthreads();
        s[t] += x;
        __syncthreads();
    }
    if (t < NCHUNK) chunk_off[t] = s[t] - v;
    if (t == 255) row_ptr[N_NODES] = s[t];
}
__global__ void scanC(const int* __restrict__ chunk_off, int* __restrict__ row_ptr,
                      int* __restrict__ cursor) {
    int idx = blockIdx.x*256 + threadIdx.x;
    if (idx < N_NODES) {
        int rp = row_ptr[idx] + chunk_off[idx >> 8];
        row_ptr[idx] = rp;
        cursor[idx] = rp;
    }
}

// Fused CSR fill + layer-1 edge weights, stored in CSR slot order.
// (Sequential Wcsr stream beats in-agg1 recompute: dstdot is NOT L2-resident
// under agg1's H1 thrash — r12 measured +25.6MB = one miss per edge.)
__global__ void fillk_w1(const int* __restrict__ row, const int* __restrict__ col,
                         const float* __restrict__ srcdot, const float* __restrict__ dstdot,
                         int* __restrict__ cursor, int* __restrict__ csr_col,
                         float* __restrict__ Wcsr) {
    int e = blockIdx.x*256 + threadIdx.x;
    if (e >= N_EDGES) return;
    int r = row[e], c = col[e];
    int pos = atomicAdd(&cursor[r], 1);
    csr_col[pos] = c;
    float4 sa = *(const float4*)(srcdot + (size_t)r*8);
    float4 sb = *(const float4*)(srcdot + (size_t)r*8 + 4);
    float4 da = *(const float4*)(dstdot + (size_t)c*8);
    float4 db = *(const float4*)(dstdot + (size_t)c*8 + 4);
    float s[8] = {sa.x+da.x, sa.y+da.y, sa.z+da.z, sa.w+da.w,
                  sb.x+db.x, sb.y+db.y, sb.z+db.z, sb.w+db.w};
    float o[8];
#pragma unroll
    for (int j = 0; j < 8; j++) {
        float lr = s[j] > 0.f ? s[j] : ALPHA*s[j];
        o[j] = __expf(-lr);
    }
    *(float4*)(Wcsr + (size_t)pos*8)     = make_float4(o[0], o[1], o[2], o[3]);
    *(float4*)(Wcsr + (size_t)pos*8 + 4) = make_float4(o[4], o[5], o[6], o[7]);
}

// ---------------------------------------------------------------------------
// Layer-1 aggregation + ELU, NATURAL head-major BF16 H1. At the structural
// fetch floor (FETCH ~391MB = 8 XCDs x full H1 sweep; rate pinned at
// ~3.7 TB/s across VALU 27-40% / occupancy 45-70% variants -> byte-bound).
// Lane l owns head l>>3: ONE Wcsr scalar per edge, one den accumulator,
// contiguous short8 output. Do not touch (r9/r10/r12 all confirm).
__global__ __launch_bounds__(256) void agg1(const unsigned short* __restrict__ H1,
                                            const float* __restrict__ Wcsr,
                                            const int* __restrict__ row_ptr,
                                            const int* __restrict__ csr_col,
                                            unsigned short* __restrict__ hcatb) {
    int wave = (blockIdx.x*256 + threadIdx.x) >> 6;
    int lane = threadIdx.x & 63;
    if (wave >= N_NODES) return;
    int start = row_ptr[wave], end = row_ptr[wave+1];
    int hd = lane >> 3;              // head owned by this lane
    float acc[8];
    float den = 0.f;
#pragma unroll
    for (int j = 0; j < 8; j++) acc[j] = 0.f;

    int k = start;
    for (; k + 4 <= end; k += 4) {
        int c0 = csr_col[k],   c1 = csr_col[k+1];
        int c2 = csr_col[k+2], c3 = csr_col[k+3];
        short8 hv0 = *(const short8*)(H1 + (size_t)c0*512 + lane*8);
        short8 hv1 = *(const short8*)(H1 + (size_t)c1*512 + lane*8);
        short8 hv2 = *(const short8*)(H1 + (size_t)c2*512 + lane*8);
        short8 hv3 = *(const short8*)(H1 + (size_t)c3*512 + lane*8);
        float w0 = Wcsr[(size_t)(k+0)*8 + hd];
        float w1 = Wcsr[(size_t)(k+1)*8 + hd];
        float w2 = Wcsr[(size_t)(k+2)*8 + hd];
        float w3 = Wcsr[(size_t)(k+3)*8 + hd];
        den += (w0 + w1) + (w2 + w3);
#pragma unroll
        for (int j = 0; j < 8; j++) {
            acc[j] = fmaf(w0, bf2f((unsigned short)hv0[j]), acc[j]);
            acc[j] = fmaf(w1, bf2f((unsigned short)hv1[j]), acc[j]);
            acc[j] = fmaf(w2, bf2f((unsigned short)hv2[j]), acc[j]);
            acc[j] = fmaf(w3, bf2f((unsigned short)hv3[j]), acc[j]);
        }
    }
    for (; k < end; ++k) {
        int c = csr_col[k];
        short8 hv = *(const short8*)(H1 + (size_t)c*512 + lane*8);
        float w = Wcsr[(size_t)k*8 + hd];
        den += w;
#pragma unroll
        for (int j = 0; j < 8; j++)
            acc[j] = fmaf(w, bf2f((unsigned short)hv[j]), acc[j]);
    }
    float rden = 1.f / (den + EPS_F);
    short8 o8;
#pragma unroll
    for (int j = 0; j < 8; j++) {
        float o = acc[j] * rden;
        o = o > 0.f ? o : (__expf(o) - 1.f);   // ELU
        o8[j] = (short)f2bf(o);
    }
    *(short8*)(hcatb + (size_t)wave*HD + lane*8) = o8;
}

// ---------------------------------------------------------------------------
// Final aggregation, software-pipelined (8-edge x 2-color batches).
// H2 is bf16: one 128B line per edge-gather.
__global__ __launch_bounds__(256) void agg2(const unsigned short* __restrict__ H2b,
                                            const float* __restrict__ src2,
                                            const float* __restrict__ dst2,
                                            const int* __restrict__ row_ptr,
                                            const int* __restrict__ csr_col,
                                            float* __restrict__ out) {
    int wave = (blockIdx.x*256 + threadIdx.x) >> 6;
    int lane = threadIdx.x & 63;
    if (wave >= N_NODES) return;
    int start = row_ptr[wave], end = row_ptr[wave+1];
    int deg = end - start;
    float s2i = src2[wave];
    int l = lane < NCLASS ? lane : 0;
    float acc = 0.f, den = 0.f;

    int colreg = 0;
    if (deg > 0) colreg = csr_col[start + (lane < deg ? lane : deg - 1)];

#define AG2_G1(T, H, IDX) do { \
    int cg_ = __builtin_amdgcn_readlane(colreg, (IDX)); \
    T = dst2[cg_]; \
    H = bf2f(H2b[(size_t)cg_*64 + l]); \
} while(0)
#define AG2_C1(T, H) do { \
    float t_ = s2i + (T); \
    t_ = t_ > 0.f ? t_ : ALPHA*t_; \
    float w_ = __expf(-t_); \
    den += w_; acc = fmaf(w_, (H), acc); \
} while(0)
#define AG2_G8(T0,T1,T2,T3,T4,T5,T6,T7,H0,H1,H2,H3,H4,H5,H6,H7,BASE) do { \
    AG2_G1(T0,H0,(BASE));   AG2_G1(T1,H1,(BASE)+1); \
    AG2_G1(T2,H2,(BASE)+2); AG2_G1(T3,H3,(BASE)+3); \
    AG2_G1(T4,H4,(BASE)+4); AG2_G1(T5,H5,(BASE)+5); \
    AG2_G1(T6,H6,(BASE)+6); AG2_G1(T7,H7,(BASE)+7); \
} while(0)
#define AG2_C8(T0,T1,T2,T3,T4,T5,T6,T7,H0,H1,H2,H3,H4,H5,H6,H7) do { \
    AG2_C1(T0,H0); AG2_C1(T1,H1); AG2_C1(T2,H2); AG2_C1(T3,H3); \
    AG2_C1(T4,H4); AG2_C1(T5,H5); AG2_C1(T6,H6); AG2_C1(T7,H7); \
} while(0)

    int lim = deg < 64 ? deg : 64;
    int nb = lim >> 3;
    int k = start;
    float ta0,ta1,ta2,ta3,ta4,ta5,ta6,ta7, ga0,ga1,ga2,ga3,ga4,ga5,ga6,ga7;
    float tb0,tb1,tb2,tb3,tb4,tb5,tb6,tb7, gb0,gb1,gb2,gb3,gb4,gb5,gb6,gb7;
    if (nb > 0) {
        AG2_G8(ta0,ta1,ta2,ta3,ta4,ta5,ta6,ta7, ga0,ga1,ga2,ga3,ga4,ga5,ga6,ga7, 0);
        int b = 1;
        for (; b + 1 < nb; b += 2) {
            AG2_G8(tb0,tb1,tb2,tb3,tb4,tb5,tb6,tb7, gb0,gb1,gb2,gb3,gb4,gb5,gb6,gb7, b*8);
            AG2_C8(ta0,ta1,ta2,ta3,ta4,ta5,ta6,ta7, ga0,ga1,ga2,ga3,ga4,ga5,ga6,ga7);
            AG2_G8(ta0,ta1,ta2,ta3,ta4,ta5,ta6,ta7, ga0,ga1,ga2,ga3,ga4,ga5,ga6,ga7, (b+1)*8);
            AG2_C8(tb0,tb1,tb2,tb3,tb4,tb5,tb6,tb7, gb0,gb1,gb2,gb3,gb4,gb5,gb6,gb7);
        }
        if (b < nb) {
            AG2_G8(tb0,tb1,tb2,tb3,tb4,tb5,tb6,tb7, gb0,gb1,gb2,gb3,gb4,gb5,gb6,gb7, b*8);
            AG2_C8(ta0,ta1,ta2,ta3,ta4,ta5,ta6,ta7, ga0,ga1,ga2,ga3,ga4,ga5,ga6,ga7);
            AG2_C8(tb0,tb1,tb2,tb3,tb4,tb5,tb6,tb7, gb0,gb1,gb2,gb3,gb4,gb5,gb6,gb7);
        } else {
            AG2_C8(ta0,ta1,ta2,ta3,ta4,ta5,ta6,ta7, ga0,ga1,ga2,ga3,ga4,ga5,ga6,ga7);
        }
        k = start + nb*8;
    }
    for (; k < end; ++k) {
        int c_ = (k - start < 64) ? __builtin_amdgcn_readlane(colreg, k - start)
                                  : csr_col[k];
        float t = dst2[c_];
        float h = bf2f(H2b[(size_t)c_*64 + l]);
        AG2_C1(t, h);
    }
#undef AG2_G1
#undef AG2_C1
#undef AG2_G8
#undef AG2_C8

    if (lane < NCLASS)
        out[(size_t)wave*NCLASS + lane] = acc / (den + EPS_F);
}

// ---------------------------------------------------------------------------
extern "C" void kernel_launch(void* const* d_in, const int* in_sizes, int n_in,
                              void* d_out, int out_size, void* d_ws, size_t ws_size,
                              hipStream_t stream) {
    const float* x       = (const float*)d_in[0];
    const float* W_heads = (const float*)d_in[1];
    const float* a_heads = (const float*)d_in[2];
    const float* W_out   = (const float*)d_in[3];
    const float* a_out   = (const float*)d_in[4];
    const int*   ei      = (const int*)d_in[5];
    const int*   row     = ei;
    const int*   col     = ei + N_EDGES;
    float* out = (float*)d_out;

    char* ws = (char*)d_ws;
    size_t off = 0;
    auto alloc = [&](size_t bytes) {
        char* p = ws + off;
        off = (off + bytes + 255) & ~(size_t)255;
        return p;
    };
    unsigned short* Wrb   = (unsigned short*)alloc((size_t)512*512*2);
    unsigned short* Wob   = (unsigned short*)alloc((size_t)64*512*2);
    unsigned short* H1    = (unsigned short*)alloc((size_t)N_NODES*HD*2);
    unsigned short* xb    = (unsigned short*)alloc((size_t)N_NODES*NFEAT*2);
    unsigned short* hcatb = xb;   // alias: xb dead after gemm1, hcatb born at agg1
    float* srcdot  = (float*)alloc((size_t)N_NODES*NHEADS*4);
    float* dstdot  = (float*)alloc((size_t)N_NODES*NHEADS*4);
    float* Wcsr    = (float*)alloc((size_t)N_EDGES*NHEADS*4);
    int*   deg     = (int*)alloc((size_t)N_NODES*4);
    int*   row_ptr = (int*)alloc((size_t)(N_NODES+1)*4);
    int*   cursor  = (int*)alloc((size_t)N_NODES*4);
    int*   ctot    = (int*)alloc(256*4);
    int*   coff    = (int*)alloc(256*4);
    int*   csr_col = (int*)alloc((size_t)N_EDGES*4);
    unsigned short* H2b = (unsigned short*)alloc((size_t)N_NODES*64*2);
    float* src2    = (float*)alloc((size_t)N_NODES*4);
    float* dst2    = (float*)alloc((size_t)N_NODES*4);
    (void)ws_size;

    const int EB = (N_EDGES + 255)/256;
    const int WB = (N_NODES*64 + 255)/256;   // wave-per-node grids

    // Layer 1 (gemm1 also produces srcdot/dstdot)
    prep<<<(N_NODES*64 + 255)/256, 256, 0, stream>>>(x, xb, W_heads, Wrb,
                                                     W_out, Wob, deg);
    {
        int rtiles = (N_NODES + 127)/128;            // 391
        int nblk = ((rtiles + 7)/8) * 16;            // 784 (2 col tiles)
        mfma_gemm1<<<nblk, 512, 0, stream>>>(xb, Wrb, a_heads, H1,
                                             srcdot, dstdot, N_NODES);
    }

    // CSR build + fused layer-1 edge weights
    histk<<<EB, 256, 0, stream>>>(row, deg);
    scanA<<<NCHUNK, 256, 0, stream>>>(deg, row_ptr, ctot);
    scanB<<<1, 256, 0, stream>>>(ctot, coff, row_ptr);
    scanC<<<NCHUNK, 256, 0, stream>>>(coff, row_ptr, cursor);
    fillk_w1<<<EB, 256, 0, stream>>>(row, col, srcdot, dstdot, cursor,
                                     csr_col, Wcsr);

    agg1<<<WB, 256, 0, stream>>>(H1, Wcsr, row_ptr, csr_col, hcatb);

    // Layer 2 (gemm2 also produces src2/dst2)
    mfma_gemm2<<<(N_NODES + 127)/128, 512, 0, stream>>>(hcatb, Wob, a_out,
                                                        H2b, src2, dst2, N_NODES);
    agg2<<<WB, 256, 0, stream>>>(H2b, src2, dst2, row_ptr, csr_col, out);
}